// Round 14
// baseline (776.548 us; speedup 1.0000x reference)
//
#include <hip/hip_runtime.h>

#define N_NODES 100000
#define N_EDGES 3200000
#define FEAT 64
#define NUM_RELS 16
#define CAP_R 8                 // slots per (dst, rel); Poisson(2) P(>8)=2.4e-4
#define OVF_CAP 32768
#define RANGES_W 4
#define NODES_PER_W 25000       // N_NODES / RANGES_W exact
#define FILL_BLOCKS 1024
#define AGG_G 4                 // nodes per agg block (1 per wave)
#define AGG_BLOCKS (NODES_PER_W / AGG_G)   // 6250
#define HS_STRIDE 1028          // floats; pad avoids systematic bank aliasing

typedef float f32x4 __attribute__((ext_vector_type(4)));
typedef float f32x16 __attribute__((ext_vector_type(16)));
typedef short s16x8 __attribute__((ext_vector_type(8)));
typedef int   i32x2 __attribute__((ext_vector_type(2)));
typedef int   i32x4 __attribute__((ext_vector_type(4)));

__device__ __forceinline__ unsigned short f32_to_bf16_rne(float x) {
    unsigned int u = __float_as_uint(x);
    unsigned int r = (u + 0x7fffu + ((u >> 16) & 1u)) >> 16;
    return (unsigned short)r;
}
__device__ __forceinline__ float bf16_to_f32(unsigned short s) {
    return __uint_as_float(((unsigned int)s) << 16);
}
__device__ __forceinline__ int rfl(int v) { return __builtin_amdgcn_readfirstlane(v); }
__device__ __forceinline__ float rflf(int v) {
    return __uint_as_float((unsigned)__builtin_amdgcn_readfirstlane(v));
}

// ---------------- conversion kernels ----------------
__global__ __launch_bounds__(256) void cvt_h_kernel(const float4* __restrict__ h4,
                                                    ushort4* __restrict__ hb4, int n4)
{
    int i = blockIdx.x * 256 + threadIdx.x;
    if (i < n4) {
        float4 v = h4[i];
        ushort4 o;
        o.x = f32_to_bf16_rne(v.x); o.y = f32_to_bf16_rne(v.y);
        o.z = f32_to_bf16_rne(v.z); o.w = f32_to_bf16_rne(v.w);
        hb4[i] = o;
    }
}

// Wt[r][o][k] = bf16(W[r][k][o])
__global__ __launch_bounds__(256) void cvt_w_kernel(const float* __restrict__ W,
                                                    unsigned short* __restrict__ Wt)
{
    int t = blockIdx.x * 256 + threadIdx.x;          // 16*64*64 threads
    int r = t >> 12, o = (t >> 6) & 63, k = t & 63;
    Wt[t] = f32_to_bf16_rne(W[(r << 12) + (k << 6) + o]);
}

// -------- fused: windowed rel-segmented fill + h-space aggregate+transform ---
// fill role: unchanged from round 13 (rel-segmented window buckets, proven).
// agg role Phase A REWRITE: static slot unrolling. Pass 1 visits slots 0..3 of
//   ALL 16 rels unconditionally (rel = compile-time const per visit -> facc[r]
//   static, branch-free, 64 independent gather chains -> deep MLP). Invalid
//   slots masked (nv=0, s=0 clamps stale pay bytes). Pass 2: slots 4..7 only
//   when cs[r]>4 (wave-uniform branch, ~5%). Phase B: MFMA contraction over
//   flattened rk (K=1024) -- verified rounds 12/13.
__global__ __launch_bounds__(256) void fill_agg2_kernel(
    const unsigned short* __restrict__ hb,   // [N][64] bf16
    const unsigned short* __restrict__ Wt,   // [16][o][k] bf16
    const int* __restrict__ src, const int* __restrict__ dst,
    const int* __restrict__ rel, const float* __restrict__ norm,
    int* __restrict__ cnt,                   // [N][16]
    int* __restrict__ ovfc, i32x4* __restrict__ ovf,
    i32x2* __restrict__ payF, const i32x2* __restrict__ payG,
    float* __restrict__ out, int fillRange, int aggRange)
{
    __shared__ float hsum[AGG_G][HS_STRIDE];         // 16.4 KB
    const int nFill = (fillRange >= 0) ? FILL_BLOCKS : 0;

    if ((int)blockIdx.x < nFill) {
        // ---- fill role ----
        const int lo = fillRange * NODES_PER_W, hi = lo + NODES_PER_W;
        for (int e = blockIdx.x * 256 + threadIdx.x; e < N_EDGES; e += nFill * 256) {
            int d = __builtin_nontemporal_load(&dst[e]);
            if (d >= lo && d < hi) {
                int s   = __builtin_nontemporal_load(&src[e]);
                int rl  = __builtin_nontemporal_load(&rel[e]);
                float nv = __builtin_nontemporal_load(&norm[e]);
                int pos = atomicAdd(&cnt[(size_t)d * 16 + rl], 1);
                if (pos < CAP_R) {
                    i32x2 p; p.x = s; p.y = __float_as_int(nv);
                    payF[((size_t)(d - lo) * 16 + rl) * CAP_R + pos] = p;
                } else {
                    int op = atomicAdd(ovfc, 1);
                    if (op < OVF_CAP) {
                        i32x4 o; o.x = d; o.y = (s << 4) | rl;
                        o.z = __float_as_int(nv); o.w = 0;
                        ovf[op] = o;
                    }
                }
            }
        }
        return;
    }

    // ---- agg role ----
    const int b     = blockIdx.x - nFill;
    const int winLo = aggRange * NODES_PER_W;
    const int base  = winLo + b * AGG_G;
    const int lane  = threadIdx.x & 63;
    const int w     = threadIdx.x >> 6;
    const int d     = base + w;                      // one node per wave

    // per-rel counts (wave-uniform)
    const int* cd = cnt + (size_t)d * 16;
    int cs[16];
    bool anyOvf = false;
    {
        i32x4 c0 = *reinterpret_cast<const i32x4*>(cd);
        i32x4 c1 = *reinterpret_cast<const i32x4*>(cd + 4);
        i32x4 c2 = *reinterpret_cast<const i32x4*>(cd + 8);
        i32x4 c3 = *reinterpret_cast<const i32x4*>(cd + 12);
        #pragma unroll
        for (int j = 0; j < 4; ++j) {
            cs[j]      = rfl(c0[j]);  cs[4 + j]  = rfl(c1[j]);
            cs[8 + j]  = rfl(c2[j]);  cs[12 + j] = rfl(c3[j]);
        }
        #pragma unroll
        for (int r = 0; r < 16; ++r) anyOvf |= (cs[r] > CAP_R);
    }

    float facc[16];
    const i32x2* pb = payG + (size_t)(d - winLo) * (16 * CAP_R);

    // Pass 1: slots 0..3 of every rel, branch-free, fully unrolled.
    #pragma unroll
    for (int r = 0; r < 16; ++r) {
        const i32x4* ps4 = reinterpret_cast<const i32x4*>(pb + r * CAP_R);
        i32x4 q01 = ps4[0];                          // slots 0,1 (16B bcast)
        i32x4 q23 = ps4[1];                          // slots 2,3
        const int n = cs[r];
        int s0 = rfl(q01.x), s1 = rfl(q01.z), s2 = rfl(q23.x), s3 = rfl(q23.z);
        float n0 = (n > 0) ? rflf(q01.y) : 0.f;
        float n1 = (n > 1) ? rflf(q01.w) : 0.f;
        float n2 = (n > 2) ? rflf(q23.y) : 0.f;
        float n3 = (n > 3) ? rflf(q23.w) : 0.f;
        s0 = (n > 0) ? s0 : 0;  s1 = (n > 1) ? s1 : 0;
        s2 = (n > 2) ? s2 : 0;  s3 = (n > 3) ? s3 : 0;
        const float h0 = bf16_to_f32(hb[((size_t)s0 << 6) + lane]);
        const float h1 = bf16_to_f32(hb[((size_t)s1 << 6) + lane]);
        const float h2 = bf16_to_f32(hb[((size_t)s2 << 6) + lane]);
        const float h3 = bf16_to_f32(hb[((size_t)s3 << 6) + lane]);
        facc[r] = fmaf(n0, h0, fmaf(n1, h1, fmaf(n2, h2, n3 * h3)));
    }

    // Pass 2: slots 4..7, only for rels with cs[r] > 4 (~5% taken, uniform).
    #pragma unroll
    for (int r = 0; r < 16; ++r) {
        if (cs[r] > 4) {
            const i32x4* ps4 = reinterpret_cast<const i32x4*>(pb + r * CAP_R);
            i32x4 q45 = ps4[2];                      // slots 4,5
            i32x4 q67 = ps4[3];                      // slots 6,7
            const int n = cs[r];
            int s4 = rfl(q45.x), s5 = rfl(q45.z), s6 = rfl(q67.x), s7 = rfl(q67.z);
            float n4 = rflf(q45.y);                  // n>4 guaranteed
            float n5 = (n > 5) ? rflf(q45.w) : 0.f;
            float n6 = (n > 6) ? rflf(q67.y) : 0.f;
            float n7 = (n > 7) ? rflf(q67.w) : 0.f;
            s5 = (n > 5) ? s5 : 0;  s6 = (n > 6) ? s6 : 0;  s7 = (n > 7) ? s7 : 0;
            const float h4 = bf16_to_f32(hb[((size_t)s4 << 6) + lane]);
            const float h5 = bf16_to_f32(hb[((size_t)s5 << 6) + lane]);
            const float h6 = bf16_to_f32(hb[((size_t)s6 << 6) + lane]);
            const float h7 = bf16_to_f32(hb[((size_t)s7 << 6) + lane]);
            facc[r] += fmaf(n4, h4, fmaf(n5, h5, fmaf(n6, h6, n7 * h7)));
        }
    }

    if (anyOvf) {                                    // exact overflow path (rare)
        const int no = min(rfl(*ovfc), OVF_CAP);
        for (int j = 0; j < no; ++j) {
            i32x4 o = ovf[j];
            if (o.x == d) {
                const int sx = o.y;
                const float nv = __uint_as_float((unsigned)o.z);
                const float c  = nv * bf16_to_f32(hb[((size_t)(sx >> 4) << 6) + lane]);
                switch (sx & 15) {
                    case 0:  facc[0]  += c; break;  case 1:  facc[1]  += c; break;
                    case 2:  facc[2]  += c; break;  case 3:  facc[3]  += c; break;
                    case 4:  facc[4]  += c; break;  case 5:  facc[5]  += c; break;
                    case 6:  facc[6]  += c; break;  case 7:  facc[7]  += c; break;
                    case 8:  facc[8]  += c; break;  case 9:  facc[9]  += c; break;
                    case 10: facc[10] += c; break;  case 11: facc[11] += c; break;
                    case 12: facc[12] += c; break;  case 13: facc[13] += c; break;
                    case 14: facc[14] += c; break;  default: facc[15] += c; break;
                }
            }
        }
    }
    // stage: hsum[node w][rk = r*64 + lane]
    #pragma unroll
    for (int rr = 0; rr < 16; ++rr)
        hsum[w][rr * 64 + lane] = facc[rr];
    __syncthreads();

    // Phase B (rounds 12/13 verified): wave w -> o-tile [w*16, w*16+16), K=1024.
    const int q  = lane & 15;
    const int g4 = lane >> 4;
    f32x4 acc = {0.f, 0.f, 0.f, 0.f};
    const unsigned short* wb = Wt + ((size_t)(w * 16 + q) << 6) + (g4 << 3);
    for (int kk = 0; kk < 32; ++kk) {
        s16x8 af = {0, 0, 0, 0, 0, 0, 0, 0};
        if (q < AGG_G) {
            const float* hp = &hsum[q][kk * 32 + g4 * 8];
            f32x4 u0 = *reinterpret_cast<const f32x4*>(hp);
            f32x4 u1 = *reinterpret_cast<const f32x4*>(hp + 4);
            #pragma unroll
            for (int j = 0; j < 4; ++j) {
                af[j]     = (short)f32_to_bf16_rne(u0[j]);
                af[4 + j] = (short)f32_to_bf16_rne(u1[j]);
            }
        }
        s16x8 bf = *reinterpret_cast<const s16x8*>(
            wb + ((size_t)(kk >> 1) << 12) + ((kk & 1) << 5));
        acc = __builtin_amdgcn_mfma_f32_16x16x32_bf16(af, bf, acc, 0, 0, 0);
    }
    if (g4 == 0) {
        #pragma unroll
        for (int rg = 0; rg < 4; ++rg)
            out[((size_t)(base + rg) << 6) + w * 16 + q] = fmaxf(acc[rg], 0.f);
    }
}

// ---------------- atomic fallback (no workspace) ----------------
__global__ __launch_bounds__(256) void rgcn_edge_kernel(
    const float* __restrict__ h, const float* __restrict__ W,
    const float* __restrict__ norm, const int* __restrict__ src,
    const int* __restrict__ dst, const int* __restrict__ rel,
    float* __restrict__ out)
{
    const int lane = threadIdx.x & 63;
    const int w    = threadIdx.x >> 6;
    const int r    = blockIdx.x & 15;
    const int inst = blockIdx.x >> 4;
    const int wavesPerRel = (gridDim.x >> 4) * 4;
    const int wi   = inst * 4 + w;

    float wreg[64];
    const float* Wr = W + (size_t)r * (FEAT * FEAT) + lane;
    #pragma unroll
    for (int d = 0; d < 64; ++d) wreg[d] = Wr[d * 64];

    const int nChunks = N_EDGES / 64;
    for (int c = wi; c < nChunks; c += wavesPerRel) {
        const int base = c * 64;
        unsigned long long m = __ballot(rel[base + lane] == r);
        while (m) {
            const int idx = __ffsll(m) - 1;
            m &= (m - 1);
            const int e = base + idx;
            const int se = __builtin_amdgcn_readfirstlane(src[e]);
            const int de = __builtin_amdgcn_readfirstlane(dst[e]);
            const float nv = __uint_as_float(
                __builtin_amdgcn_readfirstlane(__float_as_uint(norm[e])));
            const float* hp = h + ((size_t)se << 6);
            f32x16 ha, hb2, hc, hd;
            asm volatile(
                "s_load_dwordx16 %0, %4, 0x0\n\ts_load_dwordx16 %1, %4, 0x40\n\t"
                "s_load_dwordx16 %2, %4, 0x80\n\ts_load_dwordx16 %3, %4, 0xc0\n\t"
                "s_waitcnt lgkmcnt(0)"
                : "=&s"(ha), "=&s"(hb2), "=&s"(hc), "=&s"(hd) : "s"(hp));
            float a0 = 0.f, a1 = 0.f, a2 = 0.f, a3 = 0.f;
            #pragma unroll
            for (int j = 0; j < 16; ++j) {
                a0 = fmaf(ha[j], wreg[j], a0);       a1 = fmaf(hb2[j], wreg[16 + j], a1);
                a2 = fmaf(hc[j], wreg[32 + j], a2);  a3 = fmaf(hd[j], wreg[48 + j], a3);
            }
            unsafeAtomicAdd(&out[(size_t)de * FEAT + lane], ((a0 + a1) + (a2 + a3)) * nv);
        }
    }
}

__global__ __launch_bounds__(256) void relu_kernel(float4* __restrict__ out, int n4)
{
    int i = blockIdx.x * 256 + threadIdx.x;
    if (i < n4) {
        float4 v = out[i];
        v.x = fmaxf(v.x, 0.f); v.y = fmaxf(v.y, 0.f);
        v.z = fmaxf(v.z, 0.f); v.w = fmaxf(v.w, 0.f);
        out[i] = v;
    }
}

// ---------------- host ----------------
static inline size_t align256(size_t x) { return (x + 255) & ~(size_t)255; }

extern "C" void kernel_launch(void* const* d_in, const int* in_sizes, int n_in,
                              void* d_out, int out_size, void* d_ws, size_t ws_size,
                              hipStream_t stream)
{
    (void)in_sizes; (void)n_in;

    const float* h    = (const float*)d_in[0];
    const float* W    = (const float*)d_in[1];
    const float* norm = (const float*)d_in[2];
    const int*   src  = (const int*)d_in[3];
    const int*   dst  = (const int*)d_in[4];
    const int*   rel  = (const int*)d_in[5];
    float*       out  = (float*)d_out;

    const size_t szHb   = (size_t)N_NODES * FEAT * 2;              // 12.8 MB
    const size_t szWt   = (size_t)NUM_RELS * FEAT * FEAT * 2;      // 128 KB
    const size_t szCnt  = (size_t)N_NODES * NUM_RELS * 4;          // 6.4 MB
    const size_t szPayW = (size_t)NODES_PER_W * NUM_RELS * CAP_R * 8; // 25.6 MB
    const size_t szOvf  = (size_t)OVF_CAP * 16;                    // 512 KB

    const size_t need = align256(szHb) + align256(szWt) + 2 * align256(szPayW)
                      + align256(szCnt) + align256(256) + align256(szOvf); // ~71 MB

    const int n4h = N_NODES * FEAT / 4;

    if (ws_size >= need) {
        char* ws = (char*)d_ws; size_t off = 0;
        unsigned short* hb   = (unsigned short*)(ws + off); off += align256(szHb);
        unsigned short* Wt   = (unsigned short*)(ws + off); off += align256(szWt);
        i32x2*          pay0 = (i32x2*)         (ws + off); off += align256(szPayW);
        i32x2*          pay1 = (i32x2*)         (ws + off); off += align256(szPayW);
        int*            cnt  = (int*)           (ws + off); off += align256(szCnt);
        int*            ovfc = (int*)           (ws + off); off += align256(256);
        i32x4*          ovf  = (i32x4*)         (ws + off); off += align256(szOvf);

        hipLaunchKernelGGL(cvt_h_kernel, dim3((n4h + 255) / 256), dim3(256), 0, stream,
                           (const float4*)h, (ushort4*)hb, n4h);
        hipLaunchKernelGGL(cvt_w_kernel, dim3(NUM_RELS * FEAT * FEAT / 256), dim3(256),
                           0, stream, W, Wt);
        hipMemsetAsync(cnt, 0, szCnt, stream);
        hipMemsetAsync(ovfc, 0, 256, stream);

        // K0: fill(0); K1..K3: fill(r) + agg(r-1); K4: agg(3).
        i32x2* win[2] = {pay0, pay1};
        hipLaunchKernelGGL(fill_agg2_kernel, dim3(FILL_BLOCKS), dim3(256), 0, stream,
                           hb, Wt, src, dst, rel, norm, cnt, ovfc, ovf,
                           win[0], (const i32x2*)nullptr, out, 0, -1);
        for (int r = 1; r < RANGES_W; ++r) {
            hipLaunchKernelGGL(fill_agg2_kernel, dim3(FILL_BLOCKS + AGG_BLOCKS), dim3(256),
                               0, stream, hb, Wt, src, dst, rel, norm, cnt, ovfc, ovf,
                               win[r & 1], win[(r - 1) & 1], out, r, r - 1);
        }
        hipLaunchKernelGGL(fill_agg2_kernel, dim3(AGG_BLOCKS), dim3(256), 0, stream,
                           hb, Wt, src, dst, rel, norm, cnt, ovfc, ovf,
                           (i32x2*)nullptr, win[(RANGES_W - 1) & 1], out,
                           -1, RANGES_W - 1);
        return;
    }

    // last-resort atomic path
    hipMemsetAsync(d_out, 0, (size_t)out_size * sizeof(float), stream);
    hipLaunchKernelGGL(rgcn_edge_kernel, dim3(16 * 128), dim3(256), 0, stream,
                       h, W, norm, src, dst, rel, out);
    const int n4 = out_size / 4;
    hipLaunchKernelGGL(relu_kernel, dim3((n4 + 255) / 256), dim3(256), 0, stream,
                       (float4*)d_out, n4);
}

// Round 15
// 374.925 us; speedup vs baseline: 2.0712x; 2.0712x over previous
//
#include <hip/hip_runtime.h>

#define N_NODES 100000
#define N_EDGES 3200000
#define FEAT 64
#define NUM_RELS 16
#define CAP 64
#define OVF_CAP 32768
#define RANGES_W 4
#define NODES_PER_W 25000       // N_NODES / RANGES_W exact
#define FILL_BLOCKS 512
#define AGG_BLOCKS (NODES_PER_W / 4)   // 6250
#define NODE_TILES 1563         // ceil(N_NODES / 64)
#define NGEMM (NODE_TILES * 4)  // gemm blocks (4 rel-groups)

typedef float f32x4 __attribute__((ext_vector_type(4)));
typedef float f32x16 __attribute__((ext_vector_type(16)));
typedef short s16x8 __attribute__((ext_vector_type(8)));
typedef int   i32x2 __attribute__((ext_vector_type(2)));
typedef int   i32x4 __attribute__((ext_vector_type(4)));

__device__ __forceinline__ unsigned short f32_to_bf16_rne(float x) {
    unsigned int u = __float_as_uint(x);
    unsigned int r = (u + 0x7fffu + ((u >> 16) & 1u)) >> 16;
    return (unsigned short)r;
}
__device__ __forceinline__ float bf16_to_f32(unsigned short s) {
    return __uint_as_float(((unsigned int)s) << 16);
}
// T offset (in shorts) for (node s, rel r): blocked layout [N/16][R][16][64]
__device__ __forceinline__ int t_offset(int s, int r) {
    return ((s >> 4) << 14) | (r << 10) | ((s & 15) << 6);
}

// ---------------- conversion kernels ----------------
__global__ __launch_bounds__(256) void cvt_h_kernel(const float4* __restrict__ h4,
                                                    ushort4* __restrict__ hb4, int n4)
{
    int i = blockIdx.x * 256 + threadIdx.x;
    if (i < n4) {
        float4 v = h4[i];
        ushort4 o;
        o.x = f32_to_bf16_rne(v.x); o.y = f32_to_bf16_rne(v.y);
        o.z = f32_to_bf16_rne(v.z); o.w = f32_to_bf16_rne(v.w);
        hb4[i] = o;
    }
}

// Wt[r][o][k] = bf16(W[r][k][o])
__global__ __launch_bounds__(256) void cvt_w_kernel(const float* __restrict__ W,
                                                    unsigned short* __restrict__ Wt)
{
    int t = blockIdx.x * 256 + threadIdx.x;          // 16*64*64 threads
    int r = t >> 12, o = (t >> 6) & 63, k = t & 63;
    Wt[t] = f32_to_bf16_rne(W[(r << 12) + (k << 6) + o]);
}

// ---- fused phase 1 + fill(range 0): gemm split over 4 rel-groups -----------
__global__ __launch_bounds__(256) void gemm_fill_kernel(
    const unsigned short* __restrict__ hb,   // [N][64] bf16
    const unsigned short* __restrict__ Wt,   // [16][o][k] bf16
    unsigned short* __restrict__ T,          // [N/16][16][16][64] bf16
    const int* __restrict__ src, const int* __restrict__ dst,
    const int* __restrict__ rel, const float* __restrict__ norm,
    int* __restrict__ cnt, int* __restrict__ ovfc, i32x4* __restrict__ ovf,
    i32x2* __restrict__ payF)
{
    if ((int)blockIdx.x >= NGEMM) {
        // ---- fill role: range 0 (512 blocks: atomic-wall-bound, not CU-bound)
        const int b = blockIdx.x - NGEMM;
        for (int e = b * 256 + threadIdx.x; e < N_EDGES; e += FILL_BLOCKS * 256) {
            int d = __builtin_nontemporal_load(&dst[e]);
            if (d < NODES_PER_W) {
                int s   = __builtin_nontemporal_load(&src[e]);
                int rl  = __builtin_nontemporal_load(&rel[e]);
                float nv = __builtin_nontemporal_load(&norm[e]);
                int tofs = t_offset(s, rl);
                int pos = atomicAdd(&cnt[d], 1);
                if (pos < CAP) {
                    i32x2 p; p.x = tofs; p.y = __float_as_int(nv);
                    payF[(size_t)d * CAP + pos] = p;
                } else {
                    int op = atomicAdd(ovfc, 1);
                    if (op < OVF_CAP) {
                        i32x4 o; o.x = d; o.y = tofs;
                        o.z = __float_as_int(nv); o.w = 0;
                        ovf[op] = o;
                    }
                }
            }
        }
        return;
    }

    // ---- gemm role ----
    __shared__ short lds[4][16][68];                 // per-wave 16x64 tile, stride 68
    const int lane  = threadIdx.x & 63;
    const int w     = threadIdx.x >> 6;
    const int tile  = blockIdx.x >> 2;
    const int rg    = blockIdx.x & 3;                // rels rg*4..rg*4+3
    const int row0  = tile * 64 + w * 16;
    if (row0 >= N_NODES) return;                     // N%16==0: full tiles only
    const int q     = lane & 15;
    const int g4    = lane >> 4;

    const unsigned short* ap = hb + ((size_t)(row0 + q) << 6) + (g4 << 3);
    const s16x8 a0 = *reinterpret_cast<const s16x8*>(ap);
    const s16x8 a1 = *reinterpret_cast<const s16x8*>(ap + 32);

    const unsigned short* wbase = Wt + ((size_t)q << 6) + (g4 << 3);
    unsigned short* tb = T + ((size_t)(row0 >> 4) << 14);
    const int nrd = lane >> 4;
    const int c   = lane & 15;

    auto loadB = [&](s16x8* Bf, int r) {
        const unsigned short* wp = wbase + ((size_t)r << 12);
        #pragma unroll
        for (int t = 0; t < 4; ++t)
            #pragma unroll
            for (int kh = 0; kh < 2; ++kh)
                Bf[t * 2 + kh] = *reinterpret_cast<const s16x8*>(wp + (t << 10) + (kh << 5));
    };
    auto compStore = [&](const s16x8* Bf, int rr) {
        f32x4 acc[4] = {f32x4{0,0,0,0}, f32x4{0,0,0,0}, f32x4{0,0,0,0}, f32x4{0,0,0,0}};
        #pragma unroll
        for (int t = 0; t < 4; ++t) {
            acc[t] = __builtin_amdgcn_mfma_f32_16x16x32_bf16(Bf[t*2+0], a0, acc[t], 0, 0, 0);
            acc[t] = __builtin_amdgcn_mfma_f32_16x16x32_bf16(Bf[t*2+1], a1, acc[t], 0, 0, 0);
        }
        #pragma unroll
        for (int t = 0; t < 4; ++t) {
            i32x2 pk;
            pk.x = (int)((unsigned)f32_to_bf16_rne(acc[t][0]) |
                         ((unsigned)f32_to_bf16_rne(acc[t][1]) << 16));
            pk.y = (int)((unsigned)f32_to_bf16_rne(acc[t][2]) |
                         ((unsigned)f32_to_bf16_rne(acc[t][3]) << 16));
            *reinterpret_cast<i32x2*>(&lds[w][q][g4 * 4 + t * 16]) = pk;
        }
        asm volatile("s_waitcnt lgkmcnt(0)" ::: "memory");   // per-wave LDS drain
        unsigned short* tr = tb + (rr << 10);
        #pragma unroll
        for (int j = 0; j < 4; ++j) {
            const int n = nrd + 4 * j;
            i32x2 v = *reinterpret_cast<const i32x2*>(&lds[w][n][c * 4]);
            *reinterpret_cast<i32x2*>(tr + (n << 6) + (c << 2)) = v;
        }
    };

    const int r0 = rg * 4;
    s16x8 B0[8], B1[8];
    loadB(B0, r0);
    loadB(B1, r0 + 1);
    compStore(B0, r0);
    loadB(B0, r0 + 2);
    compStore(B1, r0 + 1);
    loadB(B1, r0 + 3);
    compStore(B0, r0 + 2);
    compStore(B1, r0 + 3);
}

// -------- phases 2+3 fused: windowed bucket scatter + per-dst aggregate ------
__global__ __launch_bounds__(256) void fill_agg_kernel(
    const int* __restrict__ src, const int* __restrict__ dst,
    const int* __restrict__ rel, const float* __restrict__ norm,
    int* __restrict__ cnt, int* __restrict__ ovfc, i32x4* __restrict__ ovf,
    i32x2* __restrict__ payF, const i32x2* __restrict__ payG,
    const unsigned short* __restrict__ T, float* __restrict__ out,
    int fillRange, int aggRange)
{
    const int nFill = (fillRange >= 0) ? FILL_BLOCKS : 0;
    if ((int)blockIdx.x < nFill) {
        // ---- fill role ----
        const int lo = fillRange * NODES_PER_W, hi = lo + NODES_PER_W;
        for (int e = blockIdx.x * 256 + threadIdx.x; e < N_EDGES; e += nFill * 256) {
            int d = __builtin_nontemporal_load(&dst[e]);
            if (d >= lo && d < hi) {
                int s   = __builtin_nontemporal_load(&src[e]);
                int rl  = __builtin_nontemporal_load(&rel[e]);
                float nv = __builtin_nontemporal_load(&norm[e]);
                int tofs = t_offset(s, rl);
                int pos = atomicAdd(&cnt[d], 1);
                if (pos < CAP) {
                    i32x2 p; p.x = tofs; p.y = __float_as_int(nv);
                    payF[(size_t)(d - lo) * CAP + pos] = p;
                } else {
                    int op = atomicAdd(ovfc, 1);
                    if (op < OVF_CAP) {
                        i32x4 o; o.x = d; o.y = tofs;
                        o.z = __float_as_int(nv); o.w = 0;
                        ovf[op] = o;
                    }
                }
            }
        }
    } else {
        // ---- aggregate role: unroll 8, i32x4 pay loads (2 edges/load) ----
        const int b    = blockIdx.x - nFill;
        const int lo   = aggRange * NODES_PER_W;
        const int lane = threadIdx.x & 63;
        const int d    = lo + b * 4 + (threadIdx.x >> 6);

        const int degRaw = __builtin_amdgcn_readfirstlane(cnt[d]);
        const int deg    = min(degRaw, CAP);
        const i32x2* pp  = payG + (size_t)(d - lo) * CAP;
        const i32x4* pp4 = reinterpret_cast<const i32x4*>(pp);   // 16B aligned

        float acc0 = 0.f, acc1 = 0.f;
        int i = 0;
        for (; i + 8 <= deg; i += 8) {
            i32x4 qa = __builtin_nontemporal_load(&pp4[(i >> 1) + 0]);  // e0,e1
            i32x4 qb = __builtin_nontemporal_load(&pp4[(i >> 1) + 1]);  // e2,e3
            i32x4 qc = __builtin_nontemporal_load(&pp4[(i >> 1) + 2]);  // e4,e5
            i32x4 qd = __builtin_nontemporal_load(&pp4[(i >> 1) + 3]);  // e6,e7
            const unsigned short t0 = T[(size_t)(unsigned)qa.x + lane];
            const unsigned short t1 = T[(size_t)(unsigned)qa.z + lane];
            const unsigned short t2 = T[(size_t)(unsigned)qb.x + lane];
            const unsigned short t3 = T[(size_t)(unsigned)qb.z + lane];
            const unsigned short t4 = T[(size_t)(unsigned)qc.x + lane];
            const unsigned short t5 = T[(size_t)(unsigned)qc.z + lane];
            const unsigned short t6 = T[(size_t)(unsigned)qd.x + lane];
            const unsigned short t7 = T[(size_t)(unsigned)qd.z + lane];
            acc0 = fmaf(__int_as_float(qa.y), bf16_to_f32(t0), acc0);
            acc1 = fmaf(__int_as_float(qa.w), bf16_to_f32(t1), acc1);
            acc0 = fmaf(__int_as_float(qb.y), bf16_to_f32(t2), acc0);
            acc1 = fmaf(__int_as_float(qb.w), bf16_to_f32(t3), acc1);
            acc0 = fmaf(__int_as_float(qc.y), bf16_to_f32(t4), acc0);
            acc1 = fmaf(__int_as_float(qc.w), bf16_to_f32(t5), acc1);
            acc0 = fmaf(__int_as_float(qd.y), bf16_to_f32(t6), acc0);
            acc1 = fmaf(__int_as_float(qd.w), bf16_to_f32(t7), acc1);
        }
        for (; i + 2 <= deg; i += 2) {
            i32x4 qa = __builtin_nontemporal_load(&pp4[i >> 1]);
            const unsigned short t0 = T[(size_t)(unsigned)qa.x + lane];
            const unsigned short t1 = T[(size_t)(unsigned)qa.z + lane];
            acc0 = fmaf(__int_as_float(qa.y), bf16_to_f32(t0), acc0);
            acc1 = fmaf(__int_as_float(qa.w), bf16_to_f32(t1), acc1);
        }
        if (i < deg) {
            i32x2 p = __builtin_nontemporal_load(&pp[i]);
            const unsigned short t = T[(size_t)(unsigned)p.x + lane];
            acc0 = fmaf(__int_as_float(p.y), bf16_to_f32(t), acc0);
        }
        float acc = acc0 + acc1;
        if (degRaw > CAP) {                      // exact overflow handling (rare)
            const int no = min(__builtin_amdgcn_readfirstlane(*ovfc), OVF_CAP);
            for (int j = 0; j < no; ++j) {
                i32x4 o = ovf[j];
                if (o.x == d) {
                    const unsigned short t = T[(size_t)(unsigned)o.y + lane];
                    acc = fmaf(__int_as_float(o.z), bf16_to_f32(t), acc);
                }
            }
        }
        out[((size_t)d << 6) + lane] = fmaxf(acc, 0.f);
    }
}

// ---------------- atomic fallback (no workspace) ----------------
__global__ __launch_bounds__(256) void rgcn_edge_kernel(
    const float* __restrict__ h, const float* __restrict__ W,
    const float* __restrict__ norm, const int* __restrict__ src,
    const int* __restrict__ dst, const int* __restrict__ rel,
    float* __restrict__ out)
{
    const int lane = threadIdx.x & 63;
    const int w    = threadIdx.x >> 6;
    const int r    = blockIdx.x & 15;
    const int inst = blockIdx.x >> 4;
    const int wavesPerRel = (gridDim.x >> 4) * 4;
    const int wi   = inst * 4 + w;

    float wreg[64];
    const float* Wr = W + (size_t)r * (FEAT * FEAT) + lane;
    #pragma unroll
    for (int d = 0; d < 64; ++d) wreg[d] = Wr[d * 64];

    const int nChunks = N_EDGES / 64;
    for (int c = wi; c < nChunks; c += wavesPerRel) {
        const int base = c * 64;
        unsigned long long m = __ballot(rel[base + lane] == r);
        while (m) {
            const int idx = __ffsll(m) - 1;
            m &= (m - 1);
            const int e = base + idx;
            const int se = __builtin_amdgcn_readfirstlane(src[e]);
            const int de = __builtin_amdgcn_readfirstlane(dst[e]);
            const float nv = __uint_as_float(
                __builtin_amdgcn_readfirstlane(__float_as_uint(norm[e])));
            const float* hp = h + ((size_t)se << 6);
            f32x16 ha, hb2, hc, hd;
            asm volatile(
                "s_load_dwordx16 %0, %4, 0x0\n\ts_load_dwordx16 %1, %4, 0x40\n\t"
                "s_load_dwordx16 %2, %4, 0x80\n\ts_load_dwordx16 %3, %4, 0xc0\n\t"
                "s_waitcnt lgkmcnt(0)"
                : "=&s"(ha), "=&s"(hb2), "=&s"(hc), "=&s"(hd) : "s"(hp));
            float a0 = 0.f, a1 = 0.f, a2 = 0.f, a3 = 0.f;
            #pragma unroll
            for (int j = 0; j < 16; ++j) {
                a0 = fmaf(ha[j], wreg[j], a0);       a1 = fmaf(hb2[j], wreg[16 + j], a1);
                a2 = fmaf(hc[j], wreg[32 + j], a2);  a3 = fmaf(hd[j], wreg[48 + j], a3);
            }
            unsafeAtomicAdd(&out[(size_t)de * FEAT + lane], ((a0 + a1) + (a2 + a3)) * nv);
        }
    }
}

__global__ __launch_bounds__(256) void relu_kernel(float4* __restrict__ out, int n4)
{
    int i = blockIdx.x * 256 + threadIdx.x;
    if (i < n4) {
        float4 v = out[i];
        v.x = fmaxf(v.x, 0.f); v.y = fmaxf(v.y, 0.f);
        v.z = fmaxf(v.z, 0.f); v.w = fmaxf(v.w, 0.f);
        out[i] = v;
    }
}

// ---------------- host ----------------
static inline size_t align256(size_t x) { return (x + 255) & ~(size_t)255; }

extern "C" void kernel_launch(void* const* d_in, const int* in_sizes, int n_in,
                              void* d_out, int out_size, void* d_ws, size_t ws_size,
                              hipStream_t stream)
{
    (void)in_sizes; (void)n_in;

    const float* h    = (const float*)d_in[0];
    const float* W    = (const float*)d_in[1];
    const float* norm = (const float*)d_in[2];
    const int*   src  = (const int*)d_in[3];
    const int*   dst  = (const int*)d_in[4];
    const int*   rel  = (const int*)d_in[5];
    float*       out  = (float*)d_out;

    const size_t szT    = (size_t)N_NODES * NUM_RELS * FEAT * 2;   // 204.8 MB
    const size_t szHb   = (size_t)N_NODES * FEAT * 2;              // 12.8 MB
    const size_t szWt   = (size_t)NUM_RELS * FEAT * FEAT * 2;      // 128 KB
    const size_t szCnt  = (size_t)N_NODES * 4;                     // 400 KB
    const size_t szPayW = (size_t)NODES_PER_W * CAP * 8;           // 12.8 MB per window
    const size_t szOvf  = (size_t)OVF_CAP * 16;                    // 512 KB

    const size_t needWin = align256(szT) + align256(szHb) + align256(szWt)
                         + 2 * align256(szPayW) + align256(szCnt) + align256(256)
                         + align256(szOvf);                        // ~244.3 MB (proven fit)

    const int n4h = N_NODES * FEAT / 4;

    if (ws_size >= needWin) {
        char* ws = (char*)d_ws; size_t off = 0;
        unsigned short* T    = (unsigned short*)(ws + off); off += align256(szT);
        unsigned short* hb   = (unsigned short*)(ws + off); off += align256(szHb);
        unsigned short* Wt   = (unsigned short*)(ws + off); off += align256(szWt);
        i32x2*          pay0 = (i32x2*)         (ws + off); off += align256(szPayW);
        i32x2*          pay1 = (i32x2*)         (ws + off); off += align256(szPayW);
        int*            cnt  = (int*)           (ws + off); off += align256(szCnt);
        int*            ovfc = (int*)           (ws + off); off += align256(256);
        i32x4*          ovf  = (i32x4*)         (ws + off); off += align256(szOvf);

        hipLaunchKernelGGL(cvt_h_kernel, dim3((n4h + 255) / 256), dim3(256), 0, stream,
                           (const float4*)h, (ushort4*)hb, n4h);
        hipLaunchKernelGGL(cvt_w_kernel, dim3(NUM_RELS * FEAT * FEAT / 256), dim3(256),
                           0, stream, W, Wt);
        hipMemsetAsync(cnt, 0, szCnt, stream);
        hipMemsetAsync(ovfc, 0, 256, stream);

        // K_g: gemm (rel-split) + fill(0); K1..K3: fill(r)+agg(r-1); K4: agg(3).
        hipLaunchKernelGGL(gemm_fill_kernel, dim3(NGEMM + FILL_BLOCKS), dim3(256), 0, stream,
                           hb, Wt, T, src, dst, rel, norm, cnt, ovfc, ovf, pay0);

        i32x2* win[2] = {pay0, pay1};
        for (int r = 1; r < RANGES_W; ++r) {
            hipLaunchKernelGGL(fill_agg_kernel, dim3(FILL_BLOCKS + AGG_BLOCKS), dim3(256),
                               0, stream, src, dst, rel, norm, cnt, ovfc, ovf,
                               win[r & 1], win[(r - 1) & 1], T, out, r, r - 1);
        }
        hipLaunchKernelGGL(fill_agg_kernel, dim3(AGG_BLOCKS), dim3(256), 0, stream,
                           src, dst, rel, norm, cnt, ovfc, ovf,
                           (i32x2*)nullptr, win[(RANGES_W - 1) & 1], T, out,
                           -1, RANGES_W - 1);
        return;
    }

    // last-resort atomic path
    hipMemsetAsync(d_out, 0, (size_t)out_size * sizeof(float), stream);
    hipLaunchKernelGGL(rgcn_edge_kernel, dim3(16 * 128), dim3(256), 0, stream,
                       h, W, norm, src, dst, rel, out);
    const int n4 = out_size / 4;
    hipLaunchKernelGGL(relu_kernel, dim3((n4 + 255) / 256), dim3(256), 0, stream,
                       (float4*)d_out, n4);
}